// Round 13
// baseline (67.093 us; speedup 1.0000x reference)
//
#include <hip/hip_runtime.h>
#include <cstddef>
#include <cstdint>

namespace {

constexpr int kB = 32, kT = 512, kD = 64, kP = 16, kNW = 63, kDM = 512;
constexpr int kRows = kD * kNW + kT;     // 4544 output rows per batch
constexpr int kPS = 132;                 // private slab row stride (floats)
constexpr int kNBT = kB * kD;            // 2048 temporal blocks (FIRST: LPT)
constexpr int kNBF = kB * (kT / 16);     // 1024 feature blocks (last, short)

typedef float f32x4  __attribute__((ext_vector_type(4)));
typedef short bf16x8 __attribute__((ext_vector_type(8)));

__device__ __forceinline__ unsigned short bf16_rne(float f) {
    unsigned int u = __float_as_uint(f);
    u += 0x7fffu + ((u >> 16) & 1u);
    return (unsigned short)(u >> 16);
}
__device__ __forceinline__ float bf16_f(unsigned short h) {
    return __uint_as_float(((unsigned int)h) << 16);
}

// split f into bf16 hi/lo and append to frag pair
__device__ __forceinline__ void split8(const float* v, bf16x8& hi, bf16x8& lo) {
    #pragma unroll
    for (int j = 0; j < 8; ++j) {
        const unsigned short h = bf16_rne(v[j]);
        hi[j] = (short)h;
        lo[j] = (short)bf16_rne(v[j] - bf16_f(h));
    }
}

// Single kernel; weight fragments built in-register from raw Wt/Wd (no prep
// dispatch). Temporal (long) blocks first for LPT tail. Transpose via
// wave-private LDS slabs; contiguous 512B-chunk stores.
__global__ __launch_bounds__(256)
void main_k(const float* __restrict__ x,
            const float* __restrict__ Wt, const float* __restrict__ bt,
            const float* __restrict__ Wd, const float* __restrict__ bd,
            float* __restrict__ out)
{
    __shared__ __align__(16) float slab[4 * 16 * kPS];      // 33.8 KB
    __shared__ __align__(16) unsigned short hi_s[640];
    __shared__ __align__(16) unsigned short lo_s[640];
    const int tid = threadIdx.x, lane = tid & 63, wave = tid >> 6;
    float* myslab = slab + wave * 16 * kPS;

    const int swrow = lane >> 5;           // sweep: 0/1 (row within pair)
    const int swcol = 4 * (lane & 31);     // float offset in 512B slice
    const int wrbase = (lane & 15) * kPS + 4 * (lane >> 4);  // D-frag write base

    if ((int)blockIdx.x < kNBT) {
        // ---- temporal: out[b, d*63+w, ch] = sum_p x[b,8w+p,d]*Wt[ch,p] + bt[ch]
        const int blk = blockIdx.x;
        const int b = blk >> 6, d = blk & (kD - 1);

        #pragma unroll
        for (int i = 0; i < 2; ++i) {
            const int t = tid + 256 * i;
            const float f = x[(b * kT + t) * kD + d];
            const unsigned short h = bf16_rne(f);
            hi_s[t] = h;
            lo_s[t] = bf16_rne(f - bf16_f(h));
        }
        if (tid < 128) { hi_s[512 + tid] = 0; lo_s[512 + tid] = 0; }
        __syncthreads();

        // A-frags built in-reg from raw Wt: lane holds row 16n+(lane&15),
        // k = 8*(lane>>4)+j; k>=16 is the zero pad (lanes 32-63).
        bf16x8 Ah[8], Al[8];
        {
            const int row = (lane & 15);
            const int p0  = 8 * (lane >> 4);
            #pragma unroll
            for (int i = 0; i < 8; ++i) {
                const int n = 8 * wave + i;
                float v[8];
                if (lane < 32) {
                    const f32x4* wp = (const f32x4*)(Wt + (16 * n + row) * kP + p0);
                    const f32x4 a = wp[0], c = wp[1];
                    v[0]=a.x; v[1]=a.y; v[2]=a.z; v[3]=a.w;
                    v[4]=c.x; v[5]=c.y; v[6]=c.z; v[7]=c.w;
                } else {
                    #pragma unroll
                    for (int j = 0; j < 8; ++j) v[j] = 0.f;
                }
                split8(v, Ah[i], Al[i]);
            }
        }

        const f32x4 biasv = *(const f32x4*)(bt + 128 * wave + swcol);
        float* orow = out + (size_t)b * kRows * kDM + (size_t)(d * kNW) * kDM + 128 * wave;

        for (int g = 0; g < 4; ++g) {
            const int toff = 128 * g + 8 * (lane & 15) + 8 * (lane >> 4);
            const bf16x8 Bh = *(const bf16x8*)(hi_s + toff);
            const bf16x8 Bl = *(const bf16x8*)(lo_s + toff);

            #pragma unroll
            for (int i = 0; i < 8; ++i) {
                f32x4 acc = {0.f, 0.f, 0.f, 0.f};
                acc = __builtin_amdgcn_mfma_f32_16x16x32_bf16(Ah[i], Bh, acc, 0, 0, 0);
                acc = __builtin_amdgcn_mfma_f32_16x16x32_bf16(Al[i], Bh, acc, 0, 0, 0);
                acc = __builtin_amdgcn_mfma_f32_16x16x32_bf16(Ah[i], Bl, acc, 0, 0, 0);
                *(f32x4*)(myslab + wrbase + 16 * i) = acc;
            }
            #pragma unroll
            for (int k = 0; k < 8; ++k) {
                const int r    = 2 * k + swrow;
                const int wrow = 16 * g + r;
                const f32x4 v = *(const f32x4*)(myslab + r * kPS + swcol);
                if (wrow < kNW)
                    *(f32x4*)(orow + (size_t)wrow * kDM + swcol) = v + biasv;
            }
        }
    } else {
        // ---- feature: out[b, 4032+t, ch] = sum_d x[b,t,d]*Wd[ch,d] + bd[ch]
        const int blk = blockIdx.x - kNBT;
        const int b = blk >> 5, tc = blk & 31;
        const int t  = tc * 16 + (lane & 15);
        const int d0 = 8 * (lane >> 4);

        const float* xrow = x + ((size_t)b * kT + t) * kD;
        bf16x8 Bh[2], Bl[2];
        #pragma unroll
        for (int kc = 0; kc < 2; ++kc) {
            float v[8];
            const f32x4* xp = (const f32x4*)(xrow + 32 * kc + d0);
            const f32x4 a = xp[0], c = xp[1];
            v[0]=a.x; v[1]=a.y; v[2]=a.z; v[3]=a.w;
            v[4]=c.x; v[5]=c.y; v[6]=c.z; v[7]=c.w;
            split8(v, Bh[kc], Bl[kc]);
        }

        const f32x4 biasv = *(const f32x4*)(bd + 128 * wave + swcol);
        const int row = (lane & 15);

        #pragma unroll
        for (int i = 0; i < 8; ++i) {
            const int n = 8 * wave + i;
            // A-frags in-reg from raw Wd: two k-chunks of 32
            bf16x8 Ah0, Al0, Ah1, Al1;
            {
                const float* wrow = Wd + (size_t)(16 * n + row) * kD;
                float v[8];
                const f32x4* wp0 = (const f32x4*)(wrow + d0);
                f32x4 a = wp0[0], c = wp0[1];
                v[0]=a.x; v[1]=a.y; v[2]=a.z; v[3]=a.w;
                v[4]=c.x; v[5]=c.y; v[6]=c.z; v[7]=c.w;
                split8(v, Ah0, Al0);
                const f32x4* wp1 = (const f32x4*)(wrow + 32 + d0);
                a = wp1[0]; c = wp1[1];
                v[0]=a.x; v[1]=a.y; v[2]=a.z; v[3]=a.w;
                v[4]=c.x; v[5]=c.y; v[6]=c.z; v[7]=c.w;
                split8(v, Ah1, Al1);
            }
            f32x4 acc = {0.f, 0.f, 0.f, 0.f};
            acc = __builtin_amdgcn_mfma_f32_16x16x32_bf16(Ah0, Bh[0], acc, 0, 0, 0);
            acc = __builtin_amdgcn_mfma_f32_16x16x32_bf16(Al0, Bh[0], acc, 0, 0, 0);
            acc = __builtin_amdgcn_mfma_f32_16x16x32_bf16(Ah0, Bl[0], acc, 0, 0, 0);
            acc = __builtin_amdgcn_mfma_f32_16x16x32_bf16(Ah1, Bh[1], acc, 0, 0, 0);
            acc = __builtin_amdgcn_mfma_f32_16x16x32_bf16(Al1, Bh[1], acc, 0, 0, 0);
            acc = __builtin_amdgcn_mfma_f32_16x16x32_bf16(Ah1, Bl[1], acc, 0, 0, 0);
            *(f32x4*)(myslab + wrbase + 16 * i) = acc;
        }

        float* orows = out + (size_t)b * kRows * kDM
                     + (size_t)(kD * kNW + tc * 16) * kDM + 128 * wave;
        #pragma unroll
        for (int k = 0; k < 8; ++k) {
            const int r = 2 * k + swrow;
            const f32x4 v = *(const f32x4*)(myslab + r * kPS + swcol);
            *(f32x4*)(orows + (size_t)r * kDM + swcol) = v + biasv;
        }
    }
}

} // namespace

extern "C" void kernel_launch(void* const* d_in, const int* in_sizes, int n_in,
                              void* d_out, int out_size, void* d_ws, size_t ws_size,
                              hipStream_t stream) {
    const float* x  = (const float*)d_in[0];
    const float* Wt = (const float*)d_in[1];
    const float* bt = (const float*)d_in[2];
    const float* Wd = (const float*)d_in[3];
    const float* bd = (const float*)d_in[4];
    float* out = (float*)d_out;

    hipLaunchKernelGGL(main_k, dim3(kNBT + kNBF), dim3(256), 0, stream,
                       x, Wt, bt, Wd, bd, out);
}

// Round 14
// 61.824 us; speedup vs baseline: 1.0852x; 1.0852x over previous
//
#include <hip/hip_runtime.h>
#include <cstddef>
#include <cstdint>

namespace {

constexpr int kB = 32, kT = 512, kD = 64, kP = 16, kNW = 63, kDM = 512;
constexpr int kRows = kD * kNW + kT;     // 4544 output rows per batch
constexpr int kPS = 132;                 // private slab row stride (floats)
constexpr int kNBT = kB * kD;            // 2048 temporal blocks (FIRST: LPT)
constexpr int kNBF = kB * (kT / 16);     // 1024 feature blocks (last, short)

typedef float f32x4  __attribute__((ext_vector_type(4)));
typedef short bf16x8 __attribute__((ext_vector_type(8)));

// ws layout (unsigned short units):
//   Wt frags: [n<32][part<2][lane<64][8]        at 0        (64 KB)
//   Wd frags: [n<32][kc<2][part<2][lane<64][8]  at 32768    (128 KB)
constexpr int kWdOff = 32768;

__device__ __forceinline__ unsigned short bf16_rne(float f) {
    unsigned int u = __float_as_uint(f);
    u += 0x7fffu + ((u >> 16) & 1u);
    return (unsigned short)(u >> 16);
}
__device__ __forceinline__ float bf16_f(unsigned short h) {
    return __uint_as_float(((unsigned int)h) << 16);
}

__global__ __launch_bounds__(256)
void prep_k(const float* __restrict__ Wt, const float* __restrict__ Wd,
            unsigned short* __restrict__ ws)
{
    const int gid = blockIdx.x * 256 + threadIdx.x;
    for (int e = gid; e < 32 * 64; e += gridDim.x * 256) {
        const int n = e >> 6, l = e & 63;
        unsigned short* dh = ws + ((size_t)(n * 2 + 0) * 64 + l) * 8;
        unsigned short* dl = ws + ((size_t)(n * 2 + 1) * 64 + l) * 8;
        if (l < 32) {
            const int row = 16 * n + (l & 15);
            const int p0  = 8 * (l >> 4);
            #pragma unroll
            for (int j = 0; j < 8; ++j) {
                float f = Wt[row * kP + p0 + j];
                unsigned short h = bf16_rne(f);
                dh[j] = h;
                dl[j] = bf16_rne(f - bf16_f(h));
            }
        } else {
            #pragma unroll
            for (int j = 0; j < 8; ++j) { dh[j] = 0; dl[j] = 0; }
        }
    }
    for (int e = gid; e < 32 * 2 * 64; e += gridDim.x * 256) {
        const int n = e >> 7, kc = (e >> 6) & 1, l = e & 63;
        const int row = 16 * n + (l & 15);
        const int d0  = 32 * kc + 8 * (l >> 4);
        unsigned short* dh = ws + kWdOff + ((size_t)((n * 2 + kc) * 2 + 0) * 64 + l) * 8;
        unsigned short* dl = ws + kWdOff + ((size_t)((n * 2 + kc) * 2 + 1) * 64 + l) * 8;
        #pragma unroll
        for (int j = 0; j < 8; ++j) {
            float f = Wd[row * kD + d0 + j];
            unsigned short h = bf16_rne(f);
            dh[j] = h;
            dl[j] = bf16_rne(f - bf16_f(h));
        }
    }
}

// R12 structure (proven 64.5us), block order swapped: temporal first (LPT).
__global__ __launch_bounds__(256)
void main_k(const float* __restrict__ x, const unsigned short* __restrict__ ws,
            const float* __restrict__ bt, const float* __restrict__ bd,
            float* __restrict__ out)
{
    __shared__ __align__(16) float slab[4 * 16 * kPS];      // 33.8 KB
    __shared__ __align__(16) unsigned short hi_s[640];
    __shared__ __align__(16) unsigned short lo_s[640];
    const int tid = threadIdx.x, lane = tid & 63, wave = tid >> 6;
    float* myslab = slab + wave * 16 * kPS;

    const int swrow = lane >> 5;           // sweep: 0/1 (row within pair)
    const int swcol = 4 * (lane & 31);     // float offset in 512B slice
    const int wrbase = (lane & 15) * kPS + 4 * (lane >> 4);  // D-frag write base

    if ((int)blockIdx.x < kNBT) {
        // ---- temporal: out[b, d*63+w, ch] = sum_p x[b,8w+p,d]*Wt[ch,p] + bt[ch]
        const int blk = blockIdx.x;
        const int b = blk >> 6, d = blk & (kD - 1);

        #pragma unroll
        for (int i = 0; i < 2; ++i) {
            const int t = tid + 256 * i;
            const float f = x[(b * kT + t) * kD + d];
            const unsigned short h = bf16_rne(f);
            hi_s[t] = h;
            lo_s[t] = bf16_rne(f - bf16_f(h));
        }
        if (tid < 128) { hi_s[512 + tid] = 0; lo_s[512 + tid] = 0; }
        __syncthreads();   // only barrier; no stores outstanding yet

        bf16x8 Ah[8], Al[8];
        #pragma unroll
        for (int i = 0; i < 8; ++i) {
            const int n = 8 * wave + i;
            Ah[i] = *(const bf16x8*)(ws + ((n * 2 + 0) * 64 + lane) * 8);
            Al[i] = *(const bf16x8*)(ws + ((n * 2 + 1) * 64 + lane) * 8);
        }

        const f32x4 biasv = *(const f32x4*)(bt + 128 * wave + swcol);
        float* orow = out + (size_t)b * kRows * kDM + (size_t)(d * kNW) * kDM + 128 * wave;

        for (int g = 0; g < 4; ++g) {
            const int toff = 128 * g + 8 * (lane & 15) + 8 * (lane >> 4);
            const bf16x8 Bh = *(const bf16x8*)(hi_s + toff);
            const bf16x8 Bl = *(const bf16x8*)(lo_s + toff);

            #pragma unroll
            for (int i = 0; i < 8; ++i) {
                f32x4 acc = {0.f, 0.f, 0.f, 0.f};
                acc = __builtin_amdgcn_mfma_f32_16x16x32_bf16(Ah[i], Bh, acc, 0, 0, 0);
                acc = __builtin_amdgcn_mfma_f32_16x16x32_bf16(Al[i], Bh, acc, 0, 0, 0);
                acc = __builtin_amdgcn_mfma_f32_16x16x32_bf16(Ah[i], Bl, acc, 0, 0, 0);
                *(f32x4*)(myslab + wrbase + 16 * i) = acc;
            }
            // within-wave RAW: lgkmcnt wait only, no barrier
            #pragma unroll
            for (int k = 0; k < 8; ++k) {
                const int r    = 2 * k + swrow;
                const int wrow = 16 * g + r;
                const f32x4 v = *(const f32x4*)(myslab + r * kPS + swcol);
                if (wrow < kNW)
                    *(f32x4*)(orow + (size_t)wrow * kDM + swcol) = v + biasv;
            }
        }
    } else {
        // ---- feature: out[b, 4032+t, ch] = sum_d x[b,t,d]*Wd[ch,d] + bd[ch]
        const int blk = blockIdx.x - kNBT;
        const int b = blk >> 5, tc = blk & 31;
        const int t  = tc * 16 + (lane & 15);
        const int d0 = 8 * (lane >> 4);

        const float* xrow = x + ((size_t)b * kT + t) * kD;
        bf16x8 Bh[2], Bl[2];
        #pragma unroll
        for (int kc = 0; kc < 2; ++kc) {
            #pragma unroll
            for (int j = 0; j < 8; ++j) {
                const float f = xrow[32 * kc + d0 + j];
                const unsigned short h = bf16_rne(f);
                Bh[kc][j] = (short)h;
                Bl[kc][j] = (short)bf16_rne(f - bf16_f(h));
            }
        }

        const f32x4 biasv = *(const f32x4*)(bd + 128 * wave + swcol);
        const unsigned short* wsd = ws + kWdOff;

        #pragma unroll
        for (int i = 0; i < 8; ++i) {
            const int n = 8 * wave + i;
            const bf16x8 Ah0 = *(const bf16x8*)(wsd + (((n * 2 + 0) * 2 + 0) * 64 + lane) * 8);
            const bf16x8 Al0 = *(const bf16x8*)(wsd + (((n * 2 + 0) * 2 + 1) * 64 + lane) * 8);
            const bf16x8 Ah1 = *(const bf16x8*)(wsd + (((n * 2 + 1) * 2 + 0) * 64 + lane) * 8);
            const bf16x8 Al1 = *(const bf16x8*)(wsd + (((n * 2 + 1) * 2 + 1) * 64 + lane) * 8);
            f32x4 acc = {0.f, 0.f, 0.f, 0.f};
            acc = __builtin_amdgcn_mfma_f32_16x16x32_bf16(Ah0, Bh[0], acc, 0, 0, 0);
            acc = __builtin_amdgcn_mfma_f32_16x16x32_bf16(Al0, Bh[0], acc, 0, 0, 0);
            acc = __builtin_amdgcn_mfma_f32_16x16x32_bf16(Ah0, Bl[0], acc, 0, 0, 0);
            acc = __builtin_amdgcn_mfma_f32_16x16x32_bf16(Ah1, Bh[1], acc, 0, 0, 0);
            acc = __builtin_amdgcn_mfma_f32_16x16x32_bf16(Al1, Bh[1], acc, 0, 0, 0);
            acc = __builtin_amdgcn_mfma_f32_16x16x32_bf16(Ah1, Bl[1], acc, 0, 0, 0);
            *(f32x4*)(myslab + wrbase + 16 * i) = acc;
        }

        float* orows = out + (size_t)b * kRows * kDM
                     + (size_t)(kD * kNW + tc * 16) * kDM + 128 * wave;
        #pragma unroll
        for (int k = 0; k < 8; ++k) {
            const int r = 2 * k + swrow;
            const f32x4 v = *(const f32x4*)(myslab + r * kPS + swcol);
            *(f32x4*)(orows + (size_t)r * kDM + swcol) = v + biasv;
        }
    }
}

} // namespace

extern "C" void kernel_launch(void* const* d_in, const int* in_sizes, int n_in,
                              void* d_out, int out_size, void* d_ws, size_t ws_size,
                              hipStream_t stream) {
    const float* x  = (const float*)d_in[0];
    const float* Wt = (const float*)d_in[1];
    const float* bt = (const float*)d_in[2];
    const float* Wd = (const float*)d_in[3];
    const float* bd = (const float*)d_in[4];
    float* out = (float*)d_out;
    unsigned short* ws = (unsigned short*)d_ws;   // needs 192 KB

    hipLaunchKernelGGL(prep_k, dim3(16),          dim3(256), 0, stream, Wt, Wd, ws);
    hipLaunchKernelGGL(main_k, dim3(kNBT + kNBF), dim3(256), 0, stream, x, ws, bt, bd, out);
}